// Round 12
// baseline (93.252 us; speedup 1.0000x reference)
//
#include <hip/hip_runtime.h>

// Laplacian3D: LDS plane-ring (10 slots = 160 KiB) + named-register z-ring,
// TWO steps per barrier + deferred stores (R10 structure), now with
// amdgpu_waves_per_eu(4,4).
//
// R10 retest: R10's counters showed the 2-step phase spilled (VGPR pinned 64,
// WRITE +77 MB scratch) because the backend budgets registers for 8 waves/EU
// (2 WGs/CU) while our 160 KiB LDS caps the CU at 1 WG. waves_per_eu(4,4)
// declares the truth -> 128-VGPR budget; the ~100-reg 2-phase working set
// should now be register-resident. This is the clean A/B on "fewer barriers":
// 18 barriers instead of 33, prefetch distance 6/7, stores deferred a full
// phase so the barrier's vmcnt(0) drains only aged operations.

#define NSLOT 10
#define PLANE 4096   // 64*64 floats = 16 KB
#define CHUNK 32

typedef float fx4 __attribute__((ext_vector_type(4)));

#define GLD(gsrc, ldst) __builtin_amdgcn_global_load_lds(                      \
    (const __attribute__((address_space(1))) unsigned int*)(gsrc),             \
    (__attribute__((address_space(3))) unsigned int*)(ldst), 16, 0, 0)

#define F4E(v, j) ((j) == 0 ? (v).x : (j) == 1 ? (v).y : (j) == 2 ? (v).z : (v).w)

// One z-step compute (no barrier/store). AF holds plane Z-4 on entry,
// plane Z+4 on exit (ring fill). T2..T6 = planes Z-2, Z-1, Z, Z+1, Z+2.
#define STEPB(Z, O, AF, T2, T3, T4, T5, T6, SLF, SLC)                          \
  {                                                                            \
    const float4 zm4 = AF;                                                     \
    AF = ((Z) + 4 < 64) ? *(const float4*)(&lds[SLF][foff]) : zero;            \
    const float4 zp4 = AF;                                                     \
    const float4 zm2 = T2, zm1 = T3, ctr = T4, zp1 = T5, zp2 = T6;             \
    const float* plz = &lds[SLC][0];                                           \
    const float4 wm = *(const float4*)(plz + wmoff);                           \
    const float4 wp = *(const float4*)(plz + wpoff);                           \
    const float4 ym4t = *(const float4*)(plz + yoff[0]);                       \
    const float4 ym2t = *(const float4*)(plz + yoff[1]);                       \
    const float4 ym1t = *(const float4*)(plz + yoff[2]);                       \
    const float4 yp1t = *(const float4*)(plz + yoff[3]);                       \
    const float4 yp2t = *(const float4*)(plz + yoff[4]);                       \
    const float4 yp4t = *(const float4*)(plz + yoff[5]);                       \
    const float win[12] = {wm.x * wmm, wm.y * wmm, wm.z * wmm, wm.w * wmm,     \
                           ctr.x, ctr.y, ctr.z, ctr.w,                         \
                           wp.x * wpm, wp.y * wpm, wp.z * wpm, wp.w * wpm};    \
    _Pragma("unroll")                                                          \
    for (int j = 0; j < 4; ++j) {                                              \
        const float s1 = F4E(zm1, j) + F4E(zp1, j) + win[3 + j] + win[5 + j]   \
                       + ym[2] * F4E(ym1t, j) + ym[3] * F4E(yp1t, j);          \
        const float s2 = F4E(zm2, j) + F4E(zp2, j) + win[2 + j] + win[6 + j]   \
                       + ym[1] * F4E(ym2t, j) + ym[4] * F4E(yp2t, j);          \
        const float s4 = F4E(zm4, j) + F4E(zp4, j) + win[j] + win[8 + j]       \
                       + ym[0] * F4E(ym4t, j) + ym[5] * F4E(yp4t, j);          \
        O[j] = km6 * win[4 + j] + k1 * s1 + k2 * s2 + k4 * s4;                 \
    }                                                                          \
  }

// One 2-step phase: prefetch planes z+6,z+7; flush previous phase's stores
// (COND, compile-time-uniform); compute steps z and z+1; ONE barrier.
#define PHASE(COND, IZ, A0, A1, A2, A3, A4, A5, A6, A7)                        \
  {                                                                            \
    const int z = z0 + (IZ);                                                   \
    int sp0 = slc + 6; if (sp0 >= NSLOT) sp0 -= NSLOT;                         \
    int sp1 = slc + 7; if (sp1 >= NSLOT) sp1 -= NSLOT;                         \
    if (z + 6 <= zpmax) GLD(gp, &lds[sp0][wbase]);                             \
    if (z + 7 <= zpmax) GLD(gp + PLANE, &lds[sp1][wbase]);                     \
    if (COND) {                                                                \
        __builtin_nontemporal_store(oP0, (fx4*)ops);                           \
        __builtin_nontemporal_store(oP1, (fx4*)(ops + PLANE));                 \
        ops += 2 * PLANE;                                                      \
    }                                                                          \
    int sf0 = slc + 4; if (sf0 >= NSLOT) sf0 -= NSLOT;                         \
    int sf1 = slc + 5; if (sf1 >= NSLOT) sf1 -= NSLOT;                         \
    int sc1 = slc + 1; if (sc1 >= NSLOT) sc1 -= NSLOT;                         \
    fx4 oN0, oN1;                                                              \
    STEPB(z,     oN0, A0, A2, A3, A4, A5, A6, sf0, slc)                        \
    STEPB(z + 1, oN1, A1, A3, A4, A5, A6, A7, sf1, sc1)                        \
    oP0 = oN0; oP1 = oN1;                                                      \
    __syncthreads();                                                           \
    slc += 2; if (slc >= NSLOT) slc -= NSLOT;                                  \
    gp += 2 * PLANE;                                                           \
  }

__global__ __launch_bounds__(1024)
__attribute__((amdgpu_waves_per_eu(4, 4)))
void lap3d_ph2b(
    const float* __restrict__ x, const float* __restrict__ p,
    float* __restrict__ out)
{
    __shared__ __align__(16) float lds[NSLOT][PLANE];   // 163840 B = 160 KiB

    const int tid   = threadIdx.x;
    const int bc    = blockIdx.x >> 1;        // b*64 + c
    const int chunk = blockIdx.x & 1;
    const int z0    = chunk * CHUNK;
    const int c     = bc & 63;

    const float* vol  = x   + (size_t)bc * (64 * PLANE);
    float*       ovol = out + (size_t)bc * (64 * PLANE);

    const int y     = tid >> 4;
    const int w0    = (tid & 15) << 2;
    const int foff  = tid << 2;               // y*64 + w0
    const int wbase = (tid >> 6) << 8;        // wave's float base in a plane

    const float k1  = 0.25f / (1.0f + __expf(-p[c]));
    const float k2  = 0.25f / (1.0f + __expf(-p[64 + c]));
    const float k4  = 0.25f / (1.0f + __expf(-p[128 + c]));
    const float km6 = -6.0f * (k1 + k2 + k4);

    // y-tap clamped offsets + masks (z-independent)
    const int dys[6] = {-4, -2, -1, 1, 2, 4};
    int yoff[6]; float ym[6];
#pragma unroll
    for (int k = 0; k < 6; ++k) {
        const int yy = y + dys[k];
        const bool v = (unsigned)yy < 64u;
        yoff[k] = (v ? yy : y) * 64 + w0;
        ym[k]   = v ? 1.0f : 0.0f;
    }
    // w-tap clamped offsets + masks (quad-aligned)
    const bool wmv = (w0 >= 4), wpv = (w0 <= 56);
    const int   wmoff = wmv ? foff - 4 : foff;
    const int   wpoff = wpv ? foff + 4 : foff;
    const float wmm = wmv ? 1.0f : 0.0f, wpm = wpv ? 1.0f : 0.0f;

    // last plane worth prefetching: fills reach plane z0+CHUNK+3
    const int zpmax = (z0 + CHUNK + 3 < 64) ? z0 + CHUNK + 3 : 63;

    // prologue: planes z0-4 .. z0+5 into slots q%10 (all 10 slots)
#pragma unroll
    for (int i = 0; i < NSLOT; ++i) {
        const int q = z0 - 4 + i;
        if (q >= 0 && q < 64)                 // uniform
            GLD(vol + (size_t)q * PLANE + foff, &lds[(q + NSLOT) % NSLOT][wbase]);
    }
    __syncthreads();

    const float4 zero = make_float4(0.f, 0.f, 0.f, 0.f);

    // named ring init: a_k = plane z0-4+k (k=0..7), from LDS
#define INITA(K) ((z0 - 4 + (K) >= 0)                                          \
    ? *(const float4*)(&lds[(z0 - 4 + (K) + NSLOT) % NSLOT][foff]) : zero)
    float4 a0 = INITA(0), a1 = INITA(1), a2 = INITA(2), a3 = INITA(3),
           a4 = INITA(4), a5 = INITA(5), a6 = INITA(6), a7 = INITA(7);
#undef INITA
    __syncthreads();   // ring-init reads complete before phase-0's prefetch
                       // (planes z0+6, z0+7) overwrites those slots

    int slc = z0 % NSLOT;                     // slot of plane z
    const float* gp  = vol  + (size_t)(z0 + 6) * PLANE + foff;
    float*       ops = ovol + (size_t)z0 * PLANE + foff;
    fx4 oP0, oP1;

#pragma unroll 1
    for (int ib = 0; ib < CHUNK; ib += 8) {
        PHASE(ib != 0, ib + 0, a0, a1, a2, a3, a4, a5, a6, a7)
        PHASE(1,       ib + 2, a2, a3, a4, a5, a6, a7, a0, a1)
        PHASE(1,       ib + 4, a4, a5, a6, a7, a0, a1, a2, a3)
        PHASE(1,       ib + 6, a6, a7, a0, a1, a2, a3, a4, a5)
    }

    // epilogue: outputs of steps z0+30, z0+31
    __builtin_nontemporal_store(oP0, (fx4*)ops);
    __builtin_nontemporal_store(oP1, (fx4*)(ops + PLANE));
}

extern "C" void kernel_launch(void* const* d_in, const int* in_sizes, int n_in,
                              void* d_out, int out_size, void* d_ws, size_t ws_size,
                              hipStream_t stream) {
    const float* x = (const float*)d_in[0];
    const float* p = (const float*)d_in[1];
    float* out = (float*)d_out;
    lap3d_ph2b<<<256, 1024, 0, stream>>>(x, p, out);
}

// Round 13
// 47.569 us; speedup vs baseline: 1.9603x; 1.9603x over previous
//
#include <hip/hip_runtime.h>

// Laplacian3D: TWO 512-thread blocks per CU (independent barrier domains).
// Each block owns (b, c, z-chunk, y-half): 32 output rows + 4 halo rows each
// side staged per plane (40 rows x 64 w = 10240 B/slot), 7-slot LDS ring =
// 71680 B -> 2 blocks/CU (143 KB of 160 KB). While one block drains its
// barrier (vmcnt(0)+s_barrier), the co-resident block issues memory requests
// -> fills the burst gaps that capped R5/R9/R11 at ~4.2 TB/s effective.
// z-taps from a named-register ring (init from global, coalesced, one-time);
// y-taps from LDS with NO masks: global zero-padding coincides with
// pre-zeroed halo rows (rows 0..3 for y0=0, rows 36..39 for y0=32).
// Block swizzle: the two y-halves of a volume are 8 apart in blockIdx ->
// same XCD -> shared halo rows (8 of 40) hit that XCD's L2.

#define NSLOT 7
#define SROWS 40
#define SLOTF (SROWS * 64)   // 2560 floats = 10240 B
#define PLANEF 4096          // 64*64 floats
#define CHUNK 32

typedef float fx4 __attribute__((ext_vector_type(4)));

#define GLD(gsrc, ldst) __builtin_amdgcn_global_load_lds(                      \
    (const __attribute__((address_space(1))) unsigned int*)(gsrc),             \
    (__attribute__((address_space(3))) unsigned int*)(ldst), 16, 0, 0)

#define F4E(v, j) ((j) == 0 ? (v).x : (j) == 1 ? (v).y : (j) == 2 ? (v).z : (v).w)

// One z-step. A0 = plane z-4 on entry, plane z+4 on exit (ring fill).
// A2..A6 = planes z-2, z-1, z (center), z+1, z+2.  (A1, A7 idle this step.)
#define STEP(IZ, A0, A1, A2, A3, A4, A5, A6, A7)                               \
  {                                                                            \
    const int z = z0 + (IZ);                                                   \
    if ((z + 5 < 64) && ((IZ) < CHUNK - 1)) {      /* uniform */               \
        GLD(gp, &lds[slp][dro + wvb]);                                         \
        if (tid < 64) GLD(gp + 2048, &lds[slp][dro + 2048]);                   \
    }                                                                          \
    const float4 zm4 = A0;                                                     \
    A0 = (z + 4 < 64) ? *(const float4*)(&lds[slf][lfoff]) : zero;             \
    const float4 zp4 = A0;                                                     \
    const float4 zm2 = A2, zm1 = A3, ctr = A4, zp1 = A5, zp2 = A6;             \
    const float* pl = &lds[slc][0];                                            \
    const float4 wm   = *(const float4*)(pl + wmoff);                          \
    const float4 wp   = *(const float4*)(pl + wpoff);                          \
    const float4 ym1t = *(const float4*)(pl + lfoff - 64);                     \
    const float4 yp1t = *(const float4*)(pl + lfoff + 64);                     \
    const float4 ym2t = *(const float4*)(pl + lfoff - 128);                    \
    const float4 yp2t = *(const float4*)(pl + lfoff + 128);                    \
    const float4 ym4t = *(const float4*)(pl + lfoff - 256);                    \
    const float4 yp4t = *(const float4*)(pl + lfoff + 256);                    \
    const float win[12] = {wm.x * wmm, wm.y * wmm, wm.z * wmm, wm.w * wmm,     \
                           ctr.x, ctr.y, ctr.z, ctr.w,                         \
                           wp.x * wpm, wp.y * wpm, wp.z * wpm, wp.w * wpm};    \
    fx4 o;                                                                     \
    _Pragma("unroll")                                                          \
    for (int j = 0; j < 4; ++j) {                                              \
        const float s1 = F4E(zm1, j) + F4E(zp1, j) + win[3 + j] + win[5 + j]   \
                       + F4E(ym1t, j) + F4E(yp1t, j);                          \
        const float s2 = F4E(zm2, j) + F4E(zp2, j) + win[2 + j] + win[6 + j]   \
                       + F4E(ym2t, j) + F4E(yp2t, j);                          \
        const float s4 = F4E(zm4, j) + F4E(zp4, j) + win[j] + win[8 + j]       \
                       + F4E(ym4t, j) + F4E(yp4t, j);                          \
        o[j] = km6 * win[4 + j] + k1 * s1 + k2 * s2 + k4 * s4;                 \
    }                                                                          \
    __builtin_nontemporal_store(o, (fx4*)op_);                                 \
    __syncthreads();                                                           \
    slc = (slc + 1 == NSLOT) ? 0 : slc + 1;                                    \
    slf = (slf + 1 == NSLOT) ? 0 : slf + 1;                                    \
    slp = (slp + 1 == NSLOT) ? 0 : slp + 1;                                    \
    gp += PLANEF; op_ += PLANEF;                                               \
  }

__global__ __launch_bounds__(512) void lap3d_2wg(
    const float* __restrict__ x, const float* __restrict__ p,
    float* __restrict__ out)
{
    __shared__ __align__(16) float lds[NSLOT][SLOTF];   // 71680 B

    const int tid   = threadIdx.x;
    const int g     = blockIdx.x;
    // swizzle: g = 16a + 8h + b ; u = 8a + b (vol/chunk), h = y-half.
    // pairs (g, g+8) share u and g%8 (same XCD) -> halo rows L2-local.
    const int yhalf = (g >> 3) & 1;
    const int u     = ((g >> 4) << 3) | (g & 7);        // 0..255
    const int bc    = u >> 1;
    const int chunk = u & 1;
    const int z0    = chunk * CHUNK;
    const int y0    = yhalf << 5;
    const int c     = bc & 63;
    const int ry    = yhalf ? 28 : 0;      // staging window start (global row)
    const int dro   = yhalf ? 0 : 256;     // window start offset in slot (floats)

    const float* vol  = x   + (size_t)bc * (64 * PLANEF);
    float*       ovol = out + (size_t)bc * (64 * PLANEF);

    const int y     = tid >> 4;            // 0..31 (output row within half)
    const int w0    = (tid & 15) << 2;
    const int wvb   = (tid >> 6) << 8;     // wave's float base for GLD dest
    const int sqo   = tid << 2;            // staging offset (floats)
    const int lfoff = (y + 4) * 64 + w0;   // own column in slot (floats)
    const int gfoff = (y0 + y) * 64 + w0;  // own column in plane (floats)

    const float k1  = 0.25f / (1.0f + __expf(-p[c]));
    const float k2  = 0.25f / (1.0f + __expf(-p[64 + c]));
    const float k4  = 0.25f / (1.0f + __expf(-p[128 + c]));
    const float km6 = -6.0f * (k1 + k2 + k4);

    // w-tap clamped offsets + masks (quad-aligned)
    const bool  wmv = (w0 >= 4), wpv = (w0 <= 56);
    const int   wmoff = wmv ? lfoff - 4 : lfoff;
    const int   wpoff = wpv ? lfoff + 4 : lfoff;
    const float wmm = wmv ? 1.0f : 0.0f, wpm = wpv ? 1.0f : 0.0f;

    // zero the 4 invalid halo rows (global zero-padding) in all 7 slots.
    // staging never writes these rows, so they stay zero for the whole kernel.
    if (tid < 448) {                       // waves 0..6, uniform
        const int s   = tid >> 6, q = tid & 63;
        const int row = (yhalf ? 36 : 0) + (q >> 4);
        const int col = (q & 15) << 2;
        *(fx4*)(&lds[s][row * 64 + col]) = (fx4)0.0f;
    }

    // prologue: stage planes z0..z0+4 (36 valid rows = 9216 B contiguous each)
#pragma unroll
    for (int i = 0; i < 5; ++i) {
        const int sl = (z0 + i) % NSLOT;
        const float* src = vol + (size_t)(z0 + i) * PLANEF + ry * 64 + sqo;
        GLD(src, &lds[sl][dro + wvb]);
        if (tid < 64) GLD(src + 2048, &lds[sl][dro + 2048]);   // rows 32..35
    }

    const float4 zero = make_float4(0.f, 0.f, 0.f, 0.f);

    // register z-ring init straight from global (coalesced, one-time):
    // a_k = plane z0-4+k at own column
#define INITA(K) ((z0 - 4 + (K) >= 0)                                          \
    ? *(const float4*)(vol + (size_t)(z0 - 4 + (K)) * PLANEF + gfoff) : zero)
    float4 a0 = INITA(0), a1 = INITA(1), a2 = INITA(2), a3 = INITA(3),
           a4 = INITA(4), a5 = INITA(5), a6 = INITA(6), a7 = INITA(7);
#undef INITA

    __syncthreads();   // staging + zero rows visible

    int slc = z0 % NSLOT;              // slot of plane z
    int slf = (z0 + 4) % NSLOT;        // slot of plane z+4 (ring fill)
    int slp = (z0 + 5) % NSLOT;        // slot of plane z+5 (prefetch dest)
    const float* gp  = vol  + (size_t)(z0 + 5) * PLANEF + ry * 64 + sqo;
    float*       op_ = ovol + (size_t)z0 * PLANEF + gfoff;

#pragma unroll 1
    for (int ib = 0; ib < CHUNK; ib += 8) {
        STEP(ib + 0, a0, a1, a2, a3, a4, a5, a6, a7)
        STEP(ib + 1, a1, a2, a3, a4, a5, a6, a7, a0)
        STEP(ib + 2, a2, a3, a4, a5, a6, a7, a0, a1)
        STEP(ib + 3, a3, a4, a5, a6, a7, a0, a1, a2)
        STEP(ib + 4, a4, a5, a6, a7, a0, a1, a2, a3)
        STEP(ib + 5, a5, a6, a7, a0, a1, a2, a3, a4)
        STEP(ib + 6, a6, a7, a0, a1, a2, a3, a4, a5)
        STEP(ib + 7, a7, a0, a1, a2, a3, a4, a5, a6)
    }
}

extern "C" void kernel_launch(void* const* d_in, const int* in_sizes, int n_in,
                              void* d_out, int out_size, void* d_ws, size_t ws_size,
                              hipStream_t stream) {
    const float* x = (const float*)d_in[0];
    const float* p = (const float*)d_in[1];
    float* out = (float*)d_out;
    lap3d_2wg<<<512, 512, 0, stream>>>(x, p, out);
}